// Round 8
// baseline (101.494 us; speedup 1.0000x reference)
//
#include <hip/hip_runtime.h>

// PointPillars scatter: canvas[b, c, y, x] = feat[n, c] where coords[n] = (b, _, y, x)
// R8: one contiguous write stream per block + full occupancy + XCD-pinned reads.
//   K1: map[:] = -1
//   K2: map[b*NY*NX + y*NX + x] = n          (collision-free per problem spec)
//   K3: block = (b, c, quarter-plane): 8*64*4 = 2048 blocks (8/CU -> 32
//       waves/CU, same occupancy as the 6.9 TB/s fill). Each block writes ONE
//       contiguous 160 KB output run. b = blockIdx % batch pins each sample to
//       one XCD (round-robin dispatch), so map slice (640 KB) + feat slice
//       (~3 MB) stay L2-resident per XCD. Thread: map int4 (prefetch depth 1),
//       4 masked scalar gathers of plane c, one nt fvec4 store. No transpose.

#define NXD 400
#define NYD 400
#define CCH 64
#define NXY (NXD * NYD)      // 160000 cells/sample
#define QCELLS 40000         // cells per quarter-plane
#define QCHUNK (QCELLS / 4)  // 10000 16B chunks per quarter-plane

typedef float fvec4 __attribute__((ext_vector_type(4)));
typedef int   ivec4 __attribute__((ext_vector_type(4)));

__global__ void pps_init_map(ivec4* __restrict__ map4, int total4) {
    int i = blockIdx.x * blockDim.x + threadIdx.x;
    int stride = gridDim.x * blockDim.x;
    ivec4 neg1 = {-1, -1, -1, -1};
    for (; i < total4; i += stride)
        __builtin_nontemporal_store(neg1, map4 + i);
}

__global__ void pps_build_map(const int* __restrict__ coords, int* __restrict__ map, int n) {
    int i = blockIdx.x * blockDim.x + threadIdx.x;
    if (i >= n) return;
    ivec4 c4 = *(const ivec4*)(coords + i * 4);   // (b, _, y, x)
    map[c4.x * NXY + c4.z * NXD + c4.w] = i;
}

__global__ __launch_bounds__(256) void pps_plane_stream(const float* __restrict__ feat,
                                                        const int* __restrict__ map,
                                                        float* __restrict__ out,
                                                        int batch) {
    // blockIdx.x = (c * 4 + q) * batch + b  -> consecutive blocks hit
    // different XCDs (round-robin), so each XCD owns one sample's reads.
    int bid = blockIdx.x;
    int b   = bid % 8;                 // batch == 8; % batch kept implicit
    int tmp = bid >> 3;
    int q   = tmp & 3;
    int c   = tmp >> 2;

    const ivec4* mrow4 = (const ivec4*)(map + b * NXY + q * QCELLS);
    float* ob = out + ((size_t)(b * CCH + c)) * NXY + q * QCELLS;

    int t = threadIdx.x;

    // map prefetch depth 1 (plain load: we WANT L2 allocation/reuse)
    ivec4 m = mrow4[t];

    for (int j = t; j < QCHUNK; j += 256) {
        ivec4 mc = m;
        int jn = j + 256;
        if (jn < QCHUNK) m = mrow4[jn];

        fvec4 v;
        v.x = (mc.x >= 0) ? feat[(size_t)mc.x * CCH + c] : 0.0f;  // exec-masked,
        v.y = (mc.y >= 0) ? feat[(size_t)mc.y * CCH + c] : 0.0f;  // L2-resident
        v.z = (mc.z >= 0) ? feat[(size_t)mc.z * CCH + c] : 0.0f;  // per-XCD
        v.w = (mc.w >= 0) ? feat[(size_t)mc.w * CCH + c] : 0.0f;

        __builtin_nontemporal_store(v, (fvec4*)(ob + (size_t)j * 4));
    }
}

extern "C" void kernel_launch(void* const* d_in, const int* in_sizes, int n_in,
                              void* d_out, int out_size, void* d_ws, size_t ws_size,
                              hipStream_t stream) {
    const float* feat  = (const float*)d_in[0];   // [N, 64] fp32
    const int* coords  = (const int*)d_in[1];     // [N, 4] int32 (b, _, y, x)
    float* out         = (float*)d_out;           // [B, 64, NY, NX] fp32

    const int n_pillars = in_sizes[1] / 4;
    const int batch     = out_size / (CCH * NXY); // 8
    const int total_pos = batch * NXY;            // 1.28M cells

    int* map = (int*)d_ws;                        // batch*NXY*4 = 5.12 MB

    // K1: reset map every call (d_ws not re-poisoned between replays)
    pps_init_map<<<1024, 256, 0, stream>>>((ivec4*)map, total_pos / 4);

    // K2: scatter pillar indices into the map
    pps_build_map<<<(n_pillars + 255) / 256, 256, 0, stream>>>(coords, map, n_pillars);

    // K3: 2048 blocks, one contiguous 160KB write stream each
    {
        int nblocks = CCH * 4 * batch;            // 64*4*8 = 2048
        pps_plane_stream<<<nblocks, 256, 0, stream>>>(feat, map, out, batch);
    }
}